// Round 3
// baseline (289.189 us; speedup 1.0000x reference)
//
#include <hip/hip_runtime.h>

#define NN 50000
#define NE 800000
#define NB 196          // ceil(NN/256) node buckets of 256 nodes
#define NBG 392         // 2*NB (both graphs)
#define NBLK 128        // edge chunks
#define CHUNK 6250      // NE / NBLK exactly
#define MAXB 6144       // max edges per bucket (mean 4081; +32 sigma)
// D = 128 features, HEADS=8, HID=16

typedef __bf16 bf16x8 __attribute__((ext_vector_type(8)));
typedef float  f32x4  __attribute__((ext_vector_type(4)));

__device__ __forceinline__ unsigned short f2bf(float x) {
    unsigned u = __float_as_uint(x);
    return (unsigned short)((u + 0x7FFFu + ((u >> 16) & 1u)) >> 16);   // RNE
}
__device__ __forceinline__ float bflo(unsigned u) { return __uint_as_float(u << 16); }
__device__ __forceinline__ float bfhi(unsigned u) { return __uint_as_float(u & 0xFFFF0000u); }

// async global->LDS: each lane loads 4B from its own global addr into ldsbase+lane*4
__device__ __forceinline__ void gload_lds(const unsigned* g, unsigned* l) {
    __builtin_amdgcn_global_load_lds(
        (const __attribute__((address_space(1))) unsigned*)g,
        (__attribute__((address_space(3))) unsigned*)l, 4, 0, 0);
}
__device__ __forceinline__ float readlane_f(float v, int q) {
    return __uint_as_float(__builtin_amdgcn_readlane(__float_as_uint(v), q));
}

// ---------------- phase A: per-chunk LDS histogram (chunk-major histG) + W convert ----
__global__ __launch_bounds__(1024) void histA_kernel(
    const int* __restrict__ dst1, const int* __restrict__ dst2, int* __restrict__ histG,
    const float* __restrict__ Wa, const float* __restrict__ Wb,
    unsigned short* __restrict__ Wta, unsigned short* __restrict__ Wtb)
{
    const int t = threadIdx.x, blk = blockIdx.x;
    if (blk >= NBLK) {   // W convert
        const float* W = (blk - NBLK) ? Wb : Wa;
        unsigned short* Wt = (blk - NBLK) ? Wtb : Wta;
        for (int j = t; j < 128 * 128; j += 1024) {
            int n = j >> 7, k = j & 127;
            Wt[j] = f2bf(W[k * 128 + n]);
        }
        return;
    }
    __shared__ int h[NBG];
    for (int i = t; i < NBG; i += 1024) h[i] = 0;
    __syncthreads();
    const int base = blk * CHUNK;
    for (int i = t; i < CHUNK; i += 1024) {
        atomicAdd(&h[dst1[base + i] >> 8], 1);
        atomicAdd(&h[NB + (dst2[base + i] >> 8)], 1);
    }
    __syncthreads();
    for (int i = t; i < NBG; i += 1024)
        histG[blk * NBG + i] = h[i];
}

// ---------------- phase C: scatter with LOCAL prefix computation ---------------------
__global__ __launch_bounds__(1024) void scatterC_kernel(
    const int* __restrict__ src1, const int* __restrict__ dst1,
    const int* __restrict__ src2, const int* __restrict__ dst2,
    const int* __restrict__ histG,
    int* __restrict__ gbbase, int* __restrict__ gbtot,
    unsigned int* __restrict__ bin1, unsigned int* __restrict__ bin2)
{
    __shared__ int s[512];
    __shared__ int pos[NBG];
    const int t = threadIdx.x, blk = blockIdx.x;

    int total_i = 0, pref_i = 0;
    if (t < NBG) {
        for (int c = 0; c < NBLK; c++) {
            int v = histG[c * NBG + t];          // coalesced across t
            total_i += v;
            if (c < blk) pref_i += v;
        }
    }
    if (t < 512) s[t] = (t < NBG) ? total_i : 0;
    __syncthreads();
    for (int off = 1; off < 512; off <<= 1) {
        int x = 0;
        if (t < 512 && t >= off) x = s[t - off];
        __syncthreads();
        if (t < 512) s[t] += x;
        __syncthreads();
    }
    const int sumG1 = s[NB - 1];   // inclusive over graph-1 buckets
    if (t < NBG) {
        int excl = s[t] - total_i;
        int bb = excl - ((t >= NB) ? sumG1 : 0);   // per-graph exclusive base
        pos[t] = bb + pref_i;
        if (blk == 0) { gbbase[t] = bb; gbtot[t] = total_i; }
    }
    __syncthreads();

    const int base = blk * CHUNK;
    for (int i = t; i < CHUNK; i += 1024) {
        int d = dst1[base + i], sv = src1[base + i];
        int slot = atomicAdd(&pos[d >> 8], 1);
        bin1[slot] = ((unsigned)(d & 255) << 16) | (unsigned)sv;
        d = dst2[base + i]; sv = src2[base + i];
        slot = atomicAdd(&pos[NB + (d >> 8)], 1);
        bin2[slot] = ((unsigned)(d & 255) << 16) | (unsigned)sv;
    }
}

// ---------------- bucket sort: LDS counting sort per bucket, coalesced csr flush ------
__global__ __launch_bounds__(256) void bucket_sort_kernel(
    const unsigned int* __restrict__ bin1, const unsigned int* __restrict__ bin2,
    const int* __restrict__ bbase, const int* __restrict__ btot,
    unsigned short* __restrict__ csr1, int* __restrict__ start1, int* __restrict__ deg1,
    unsigned short* __restrict__ csr2, int* __restrict__ start2, int* __restrict__ deg2)
{
    __shared__ int lcnt[256];
    __shared__ int sc[256];
    __shared__ int oat[256];
    __shared__ unsigned short outb[MAXB];
    const int t = threadIdx.x;
    const int g = (blockIdx.x >= NB) ? 1 : 0;
    const int b = blockIdx.x - g * NB;
    const unsigned int* bin = g ? bin2 : bin1;
    unsigned short* csr = g ? csr2 : csr1;
    int* start = g ? start2 : start1;
    int* deg   = g ? deg2 : deg1;

    const int base = bbase[g * NB + b];
    const int tot = min(btot[g * NB + b], MAXB);

    lcnt[t] = 0;
    __syncthreads();
    for (int i = t; i < tot; i += 256) atomicAdd(&lcnt[bin[base + i] >> 16], 1);
    __syncthreads();
    sc[t] = lcnt[t];
    __syncthreads();
    for (int off = 1; off < 256; off <<= 1) {
        int x = (t >= off) ? sc[t - off] : 0;
        __syncthreads();
        sc[t] += x;
        __syncthreads();
    }
    const int ex = sc[t] - lcnt[t];
    oat[t] = ex;
    __syncthreads();
    for (int i = t; i < tot; i += 256) {
        unsigned v = bin[base + i];
        int slot = atomicAdd(&oat[v >> 16], 1);
        outb[slot] = (unsigned short)(v & 0xFFFFu);
    }
    __syncthreads();
    for (int i = t; i < tot; i += 256) csr[base + i] = outb[i];
    int nd = b * 256 + t;
    if (nd < NN) { start[nd] = base + ex; deg[nd] = lcnt[t]; }
}

// ---------------- MFMA GEMM (fp32 in): Y = X @ W + bias, X hi/lo split (2 MFMAs) ------
__global__ __launch_bounds__(256) void mfma_gemm_kernel(
    const float* __restrict__ X, const unsigned short* __restrict__ Wt,
    const float* __restrict__ bias, float* __restrict__ Y,
    unsigned short* __restrict__ Ybf, int nrows)
{
    __shared__ unsigned short Wl[128 * 128];   // 32 KB, granule-swizzled
    const int t = threadIdx.x;
    const int lane = t & 63;
    const int wv = t >> 6;
    const int row0 = blockIdx.x * 64;
    const int m16 = lane & 15;
    const int quad = lane >> 4;

    {
        const uint4* Wg = (const uint4*)Wt;
        #pragma unroll
        for (int i = 0; i < 8; i++) {
            int gi = t + i * 256;
            int n = gi >> 4, g = gi & 15;
            uint4 v = Wg[gi];
            *(uint4*)&Wl[n * 128 + (((g ^ (n & 15)) << 3))] = v;
        }
    }

    const int arow = row0 + wv * 16 + m16;
    const bool valid = (arow < nrows);
    const float4* X4 = (const float4*)X;
    float4 xr[8];
    #pragma unroll
    for (int kc = 0; kc < 4; kc++) {
        if (valid) {
            int gidx = arow * 32 + kc * 8 + quad * 2;
            xr[kc * 2]     = X4[gidx];
            xr[kc * 2 + 1] = X4[gidx + 1];
        } else {
            xr[kc * 2] = xr[kc * 2 + 1] = make_float4(0.f, 0.f, 0.f, 0.f);
        }
    }
    __syncthreads();

    f32x4 acc[8];
    #pragma unroll
    for (int nt = 0; nt < 8; nt++) acc[nt] = (f32x4){0.f, 0.f, 0.f, 0.f};

    #pragma unroll
    for (int kc = 0; kc < 4; kc++) {
        union { unsigned short u[8]; bf16x8 v; } ah, al;
        float f[8] = { xr[kc*2].x, xr[kc*2].y, xr[kc*2].z, xr[kc*2].w,
                       xr[kc*2+1].x, xr[kc*2+1].y, xr[kc*2+1].z, xr[kc*2+1].w };
        #pragma unroll
        for (int j = 0; j < 8; j++) {
            unsigned u = __float_as_uint(f[j]);
            ah.u[j] = (unsigned short)(u >> 16);
            al.u[j] = f2bf(f[j] - __uint_as_float(u & 0xFFFF0000u));
        }
        const int sgbase = (kc * 4 + quad);
        #pragma unroll
        for (int nt = 0; nt < 8; nt++) {
            const int n = nt * 16 + m16;
            bf16x8 b = *(const bf16x8*)&Wl[n * 128 + ((sgbase ^ m16) << 3)];
            acc[nt] = __builtin_amdgcn_mfma_f32_16x16x32_bf16(ah.v, b, acc[nt], 0, 0, 0);
            acc[nt] = __builtin_amdgcn_mfma_f32_16x16x32_bf16(al.v, b, acc[nt], 0, 0, 0);
        }
    }

    #pragma unroll
    for (int nt = 0; nt < 8; nt++) {
        const int col = nt * 16 + m16;
        const float bc = bias[col];
        #pragma unroll
        for (int r = 0; r < 4; r++) {
            int row = row0 + wv * 16 + quad * 4 + r;
            if (row < nrows) {
                float val = acc[nt][r] + bc;
                if (Y)   Y[(long)row * 128 + col] = val;
                if (Ybf) Ybf[(long)row * 128 + col] = f2bf(val);
            }
        }
    }
}

// ---------------- MFMA GEMM (bf16 in): Y = Xbf @ W + bias (1 MFMA per tile) -----------
__global__ __launch_bounds__(256) void mfma_gemm_bf16_kernel(
    const unsigned short* __restrict__ Xbf, const unsigned short* __restrict__ Wt,
    const float* __restrict__ bias, float* __restrict__ Y, int nrows)
{
    __shared__ unsigned short Wl[128 * 128];
    const int t = threadIdx.x;
    const int lane = t & 63;
    const int wv = t >> 6;
    const int row0 = blockIdx.x * 64;
    const int m16 = lane & 15;
    const int quad = lane >> 4;

    {
        const uint4* Wg = (const uint4*)Wt;
        #pragma unroll
        for (int i = 0; i < 8; i++) {
            int gi = t + i * 256;
            int n = gi >> 4, g = gi & 15;
            uint4 v = Wg[gi];
            *(uint4*)&Wl[n * 128 + (((g ^ (n & 15)) << 3))] = v;
        }
    }

    const int arow = row0 + wv * 16 + m16;
    const bool valid = (arow < nrows);
    const uint4* X16 = (const uint4*)Xbf;
    union { uint4 u; bf16x8 v; } xr[4];
    #pragma unroll
    for (int kc = 0; kc < 4; kc++) {
        if (valid) xr[kc].u = X16[arow * 16 + kc * 4 + quad];
        else       xr[kc].u = make_uint4(0, 0, 0, 0);
    }
    __syncthreads();

    f32x4 acc[8];
    #pragma unroll
    for (int nt = 0; nt < 8; nt++) acc[nt] = (f32x4){0.f, 0.f, 0.f, 0.f};

    #pragma unroll
    for (int kc = 0; kc < 4; kc++) {
        const int sgbase = (kc * 4 + quad);
        #pragma unroll
        for (int nt = 0; nt < 8; nt++) {
            const int n = nt * 16 + m16;
            bf16x8 b = *(const bf16x8*)&Wl[n * 128 + ((sgbase ^ m16) << 3)];
            acc[nt] = __builtin_amdgcn_mfma_f32_16x16x32_bf16(xr[kc].v, b, acc[nt], 0, 0, 0);
        }
    }

    #pragma unroll
    for (int nt = 0; nt < 8; nt++) {
        const int col = nt * 16 + m16;
        const float bc = bias[col];
        #pragma unroll
        for (int r = 0; r < 4; r++) {
            int row = row0 + wv * 16 + quad * 4 + r;
            if (row < nrows) Y[(long)row * 128 + col] = acc[nt][r] + bc;
        }
    }
}

// ---------------- fused gather + attention: one wave per node, both graphs -------------
// Round-12: async global_load_lds staging. All <=32+32 edge-row loads are issued
// fire-and-forget into this wave's private LDS region (no VGPR destinations -> the
// compiler CANNOT register-sink them), one s_waitcnt vmcnt(0), then consume from LDS.
// Src-norms fetched lane-parallel (1 VMEM per graph), broadcast via readlane at
// consume. 16 KB LDS/wave => 5 blocks/CU (10 waves, ~31% occ) but ~640 loads in
// flight per CU vs ~176 before.
__global__ __launch_bounds__(128) void gather_attn_kernel(
    const unsigned int* __restrict__ hfb,
    const unsigned short* __restrict__ csr1, const int* __restrict__ start1,
    const int* __restrict__ deg1, const float* __restrict__ norm1,
    const unsigned short* __restrict__ csr2, const int* __restrict__ start2,
    const int* __restrict__ deg2, const float* __restrict__ norm2,
    const float* __restrict__ al, const float* __restrict__ ar,
    unsigned int* __restrict__ outb)
{
    __shared__ unsigned stage[2 * 64 * 64];        // 2 waves x 64 slots x 256B = 32 KB
    const int lane = threadIdx.x & 63;
    int node = (blockIdx.x * 128 + threadIdx.x) >> 6;
    if (node >= NN) return;
    node = __builtin_amdgcn_readfirstlane(node);   // wave-uniform -> SGPR
    unsigned* mybuf = stage + ((threadIdx.x >> 6) << 12);

    // own-feature load (attention self term) — independent, issue first
    const unsigned uf = hfb[(long)node * 64 + lane];

    const int st1 = start1[node], dg1 = deg1[node];
    const int st2 = start2[node], dg2 = deg2[node];
    const int nb1 = (dg1 < 32) ? dg1 : 32;
    const int nb2 = (dg2 < 32) ? dg2 : 32;

    // coalesced edge-id loads + lane-parallel src-norm loads (1 VMEM each)
    int myc1 = (lane < nb1) ? (int)csr1[st1 + lane] : 0;
    int myc2 = (lane < nb2) ? (int)csr2[st2 + lane] : 0;
    const float nv1 = norm1[myc1];
    const float nv2 = norm2[myc2];

    // ---- issue phase: async loads into LDS, 8-groups with uniform branch + clamp ----
    #pragma unroll
    for (int g8 = 0; g8 < 4; g8++) {
        if (g8 * 8 < nb1) {
            #pragma unroll
            for (int k = 0; k < 8; k++) {
                int q = g8 * 8 + k;
                int qq = (q < nb1) ? q : (nb1 - 1);      // clamp: dup loads MSHR-merge
                int s = __builtin_amdgcn_readlane(myc1, qq);
                gload_lds(&hfb[(long)s * 64 + lane], &mybuf[q * 64]);
            }
        }
    }
    #pragma unroll
    for (int g8 = 0; g8 < 4; g8++) {
        if (g8 * 8 < nb2) {
            #pragma unroll
            for (int k = 0; k < 8; k++) {
                int q = g8 * 8 + k;
                int qq = (q < nb2) ? q : (nb2 - 1);
                int s = __builtin_amdgcn_readlane(myc2, qq);
                gload_lds(&hfb[(long)s * 64 + lane], &mybuf[(32 + q) * 64]);
            }
        }
    }

    // single latency exposure for the whole node
    asm volatile("s_waitcnt vmcnt(0)" ::: "memory");
    __builtin_amdgcn_sched_barrier(0);

    // ---- consume phase: LDS reads + fma with readlane-broadcast src norm ----
    float2 acc1 = make_float2(0.f, 0.f), acc2 = make_float2(0.f, 0.f);
    #pragma unroll 4
    for (int q = 0; q < nb1; q++) {
        unsigned u = mybuf[q * 64 + lane];
        float n = readlane_f(nv1, q);
        acc1.x = fmaf(bflo(u), n, acc1.x);
        acc1.y = fmaf(bfhi(u), n, acc1.y);
    }
    #pragma unroll 4
    for (int q = 0; q < nb2; q++) {
        unsigned u = mybuf[(32 + q) * 64 + lane];
        float n = readlane_f(nv2, q);
        acc2.x = fmaf(bflo(u), n, acc2.x);
        acc2.y = fmaf(bfhi(u), n, acc2.y);
    }

    // ---- rare tails (P(deg>32) ~ 1e-4): serial, correctness path ----
    for (int e = 32; e < dg1; e++) {
        int s = (int)csr1[st1 + e];
        float n = norm1[s];
        unsigned u = hfb[(long)s * 64 + lane];
        acc1.x = fmaf(bflo(u), n, acc1.x);
        acc1.y = fmaf(bfhi(u), n, acc1.y);
    }
    for (int e = 32; e < dg2; e++) {
        int s = (int)csr2[st2 + e];
        float n = norm2[s];
        unsigned u = hfb[(long)s * 64 + lane];
        acc2.x = fmaf(bflo(u), n, acc2.x);
        acc2.y = fmaf(bfhi(u), n, acc2.y);
    }

    // outer (dst) norm
    const float nn1 = norm1[node], nn2 = norm2[node];
    acc1.x *= nn1; acc1.y *= nn1;
    acc2.x *= nn2; acc2.y *= nn2;

    // attention combine in flat-reshape space: lane owns cols {2*lane, 2*lane+1}
    const int cc = lane >> 3;
    const int m = node * 8 + cc;
    const int head = m / NN;
    const int hid = (2 * lane) & 15;
    const float fx = bflo(uf), fy = bfhi(uf);
    const float av0 = al[head * 16 + hid], av1 = al[head * 16 + hid + 1];
    const float rv0 = ar[head * 16 + hid], rv1 = ar[head * 16 + hid + 1];
    float s_ai = fx * av0 + fy * av1;
    float s1 = acc1.x * rv0 + acc1.y * rv1;
    float s2 = acc2.x * rv0 + acc2.y * rv1;
    s_ai += __shfl_xor(s_ai, 1); s_ai += __shfl_xor(s_ai, 2); s_ai += __shfl_xor(s_ai, 4);
    s1   += __shfl_xor(s1, 1);   s1   += __shfl_xor(s1, 2);   s1   += __shfl_xor(s1, 4);
    s2   += __shfl_xor(s2, 1);   s2   += __shfl_xor(s2, 2);   s2   += __shfl_xor(s2, 4);
    float x1 = s_ai + s1; x1 = x1 > 0.f ? x1 : 0.2f * x1;
    float x2 = s_ai + s2; x2 = x2 > 0.f ? x2 : 0.2f * x2;
    float e1 = fminf(expf(x1), 10.f);
    float e2 = fminf(expf(x2), 10.f);
    float inv = 1.f / (e1 + e2);
    float w1 = e1 * inv, w2 = e2 * inv;
    float ox = w1 * acc1.x + w2 * acc2.x;
    float oy = w1 * acc1.y + w2 * acc2.y;
    outb[(long)node * 64 + lane] = (unsigned)f2bf(ox) | ((unsigned)f2bf(oy) << 16);
}

extern "C" void kernel_launch(void* const* d_in, const int* in_sizes, int n_in,
                              void* d_out, int out_size, void* d_ws, size_t ws_size,
                              hipStream_t stream)
{
    const float* h     = (const float*)d_in[0];
    const int*   src1  = (const int*)  d_in[1];
    const int*   dst1  = (const int*)  d_in[2];
    const int*   src2  = (const int*)  d_in[3];
    const int*   dst2  = (const int*)  d_in[4];
    const float* norm1 = (const float*)d_in[5];
    const float* norm2 = (const float*)d_in[6];
    const float* W_lin = (const float*)d_in[7];
    const float* b_lin = (const float*)d_in[8];
    const float* al    = (const float*)d_in[9];
    const float* ar    = (const float*)d_in[10];
    const float* W_fc  = (const float*)d_in[11];
    const float* b_fc  = (const float*)d_in[12];
    float* out = (float*)d_out;

    // workspace layout
    unsigned short* hfb  = (unsigned short*)d_ws;         // NN*128 bf16 = 12.8 MB
    unsigned short* outbf = hfb + (size_t)NN * 128;       // NN*128 bf16 = 12.8 MB
    unsigned int* bin1 = (unsigned int*)(outbf + (size_t)NN * 128);  // NE u32
    unsigned int* bin2 = bin1 + NE;                       // NE u32
    unsigned short* csr1 = (unsigned short*)(bin2 + NE);  // NE u16
    unsigned short* csr2 = csr1 + NE;                     // NE u16
    unsigned short* WtL  = csr2 + NE;                     // 16384 u16
    unsigned short* WtF  = WtL + 128 * 128;               // 16384 u16
    int* histG  = (int*)(WtF + 128 * 128);                // NBLK*NBG ints = 200 KB
    int* btot   = histG + NBLK * NBG;                     // 392
    int* bbase  = btot + NBG;                             // 392
    int* start1 = bbase + NBG;
    int* start2 = start1 + NN;
    int* deg1   = start2 + NN;
    int* deg2   = deg1 + NN;

    // 1) histogram (chunk-major) + one-time W bf16 conversion
    histA_kernel<<<NBLK + 2, 1024, 0, stream>>>(dst1, dst2, histG, W_lin, W_fc, WtL, WtF);

    // 2) hfb = bf16(h @ W_lin + b_lin)
    mfma_gemm_kernel<<<(NN + 63) / 64, 256, 0, stream>>>(h, WtL, b_lin, nullptr, hfb, NN);

    // 3) deterministic scatter (computes its own prefix sums; publishes bbase/btot)
    scatterC_kernel<<<NBLK, 1024, 0, stream>>>(src1, dst1, src2, dst2, histG,
                                               bbase, btot, bin1, bin2);

    // 4) per-bucket LDS counting sort -> u16 CSR + start/deg
    bucket_sort_kernel<<<NBG, 256, 0, stream>>>(bin1, bin2, bbase, btot,
                                                csr1, start1, deg1,
                                                csr2, start2, deg2);

    // 5) fused gather (both graphs) + attention combine -> bf16
    gather_attn_kernel<<<(NN + 1) / 2, 128, 0, stream>>>(
        (const unsigned int*)hfb,
        csr1, start1, deg1, norm1,
        csr2, start2, deg2, norm2,
        al, ar, (unsigned int*)outbf);

    // 6) out = outbf @ W_fc + b_fc
    mfma_gemm_bf16_kernel<<<(NN + 63) / 64, 256, 0, stream>>>(outbf, WtF, b_fc, out, NN);
}

// Round 4
// 260.170 us; speedup vs baseline: 1.1115x; 1.1115x over previous
//
#include <hip/hip_runtime.h>

#define NN 50000
#define NE 800000
#define NB 196          // ceil(NN/256) node buckets of 256 nodes
#define NBG 392         // 2*NB (both graphs)
#define NBLK 128        // edge chunks
#define CHUNK 6250      // NE / NBLK exactly
#define MAXB 6144       // max edges per bucket (mean 4081; +32 sigma)
// D = 128 features, HEADS=8, HID=16

typedef __bf16 bf16x8 __attribute__((ext_vector_type(8)));
typedef float  f32x4  __attribute__((ext_vector_type(4)));

__device__ __forceinline__ unsigned short f2bf(float x) {
    unsigned u = __float_as_uint(x);
    return (unsigned short)((u + 0x7FFFu + ((u >> 16) & 1u)) >> 16);   // RNE
}
__device__ __forceinline__ float bf2f(unsigned short u) {
    return __uint_as_float(((unsigned)u) << 16);
}

// ---------------- phase A: per-chunk LDS histogram (chunk-major histG) + W convert ----
__global__ __launch_bounds__(1024) void histA_kernel(
    const int* __restrict__ dst1, const int* __restrict__ dst2, int* __restrict__ histG,
    const float* __restrict__ Wa, const float* __restrict__ Wb,
    unsigned short* __restrict__ Wta, unsigned short* __restrict__ Wtb)
{
    const int t = threadIdx.x, blk = blockIdx.x;
    if (blk >= NBLK) {   // W convert
        const float* W = (blk - NBLK) ? Wb : Wa;
        unsigned short* Wt = (blk - NBLK) ? Wtb : Wta;
        for (int j = t; j < 128 * 128; j += 1024) {
            int n = j >> 7, k = j & 127;
            Wt[j] = f2bf(W[k * 128 + n]);
        }
        return;
    }
    __shared__ int h[NBG];
    for (int i = t; i < NBG; i += 1024) h[i] = 0;
    __syncthreads();
    const int base = blk * CHUNK;
    for (int i = t; i < CHUNK; i += 1024) {
        atomicAdd(&h[dst1[base + i] >> 8], 1);
        atomicAdd(&h[NB + (dst2[base + i] >> 8)], 1);
    }
    __syncthreads();
    for (int i = t; i < NBG; i += 1024)
        histG[blk * NBG + i] = h[i];
}

// ---------------- phase C: scatter with LOCAL prefix computation ---------------------
__global__ __launch_bounds__(1024) void scatterC_kernel(
    const int* __restrict__ src1, const int* __restrict__ dst1,
    const int* __restrict__ src2, const int* __restrict__ dst2,
    const int* __restrict__ histG,
    int* __restrict__ gbbase, int* __restrict__ gbtot,
    unsigned int* __restrict__ bin1, unsigned int* __restrict__ bin2)
{
    __shared__ int s[512];
    __shared__ int pos[NBG];
    const int t = threadIdx.x, blk = blockIdx.x;

    int total_i = 0, pref_i = 0;
    if (t < NBG) {
        for (int c = 0; c < NBLK; c++) {
            int v = histG[c * NBG + t];          // coalesced across t
            total_i += v;
            if (c < blk) pref_i += v;
        }
    }
    if (t < 512) s[t] = (t < NBG) ? total_i : 0;
    __syncthreads();
    for (int off = 1; off < 512; off <<= 1) {
        int x = 0;
        if (t < 512 && t >= off) x = s[t - off];
        __syncthreads();
        if (t < 512) s[t] += x;
        __syncthreads();
    }
    const int sumG1 = s[NB - 1];   // inclusive over graph-1 buckets
    if (t < NBG) {
        int excl = s[t] - total_i;
        int bb = excl - ((t >= NB) ? sumG1 : 0);   // per-graph exclusive base
        pos[t] = bb + pref_i;
        if (blk == 0) { gbbase[t] = bb; gbtot[t] = total_i; }
    }
    __syncthreads();

    const int base = blk * CHUNK;
    for (int i = t; i < CHUNK; i += 1024) {
        int d = dst1[base + i], sv = src1[base + i];
        int slot = atomicAdd(&pos[d >> 8], 1);
        bin1[slot] = ((unsigned)(d & 255) << 16) | (unsigned)sv;
        d = dst2[base + i]; sv = src2[base + i];
        slot = atomicAdd(&pos[NB + (d >> 8)], 1);
        bin2[slot] = ((unsigned)(d & 255) << 16) | (unsigned)sv;
    }
}

// ---------------- bucket sort: LDS counting sort per bucket, coalesced csr flush ------
__global__ __launch_bounds__(256) void bucket_sort_kernel(
    const unsigned int* __restrict__ bin1, const unsigned int* __restrict__ bin2,
    const int* __restrict__ bbase, const int* __restrict__ btot,
    unsigned short* __restrict__ csr1, int* __restrict__ start1, int* __restrict__ deg1,
    unsigned short* __restrict__ csr2, int* __restrict__ start2, int* __restrict__ deg2)
{
    __shared__ int lcnt[256];
    __shared__ int sc[256];
    __shared__ int oat[256];
    __shared__ unsigned short outb[MAXB];
    const int t = threadIdx.x;
    const int g = (blockIdx.x >= NB) ? 1 : 0;
    const int b = blockIdx.x - g * NB;
    const unsigned int* bin = g ? bin2 : bin1;
    unsigned short* csr = g ? csr2 : csr1;
    int* start = g ? start2 : start1;
    int* deg   = g ? deg2 : deg1;

    const int base = bbase[g * NB + b];
    const int tot = min(btot[g * NB + b], MAXB);

    lcnt[t] = 0;
    __syncthreads();
    for (int i = t; i < tot; i += 256) atomicAdd(&lcnt[bin[base + i] >> 16], 1);
    __syncthreads();
    sc[t] = lcnt[t];
    __syncthreads();
    for (int off = 1; off < 256; off <<= 1) {
        int x = (t >= off) ? sc[t - off] : 0;
        __syncthreads();
        sc[t] += x;
        __syncthreads();
    }
    const int ex = sc[t] - lcnt[t];
    oat[t] = ex;
    __syncthreads();
    for (int i = t; i < tot; i += 256) {
        unsigned v = bin[base + i];
        int slot = atomicAdd(&oat[v >> 16], 1);
        outb[slot] = (unsigned short)(v & 0xFFFFu);
    }
    __syncthreads();
    for (int i = t; i < tot; i += 256) csr[base + i] = outb[i];
    int nd = b * 256 + t;
    if (nd < NN) { start[nd] = base + ex; deg[nd] = lcnt[t]; }
}

// ---------------- MFMA GEMM (fp32 in): halves -> YA (cols 0-63), YB (cols 64-127) -----
__global__ __launch_bounds__(256) void mfma_gemm_kernel(
    const float* __restrict__ X, const unsigned short* __restrict__ Wt,
    const float* __restrict__ bias,
    unsigned short* __restrict__ YA, unsigned short* __restrict__ YB, int nrows)
{
    __shared__ unsigned short Wl[128 * 128];   // 32 KB, granule-swizzled
    const int t = threadIdx.x;
    const int lane = t & 63;
    const int wv = t >> 6;
    const int row0 = blockIdx.x * 64;
    const int m16 = lane & 15;
    const int quad = lane >> 4;

    {
        const uint4* Wg = (const uint4*)Wt;
        #pragma unroll
        for (int i = 0; i < 8; i++) {
            int gi = t + i * 256;
            int n = gi >> 4, g = gi & 15;
            uint4 v = Wg[gi];
            *(uint4*)&Wl[n * 128 + (((g ^ (n & 15)) << 3))] = v;
        }
    }

    const int arow = row0 + wv * 16 + m16;
    const bool valid = (arow < nrows);
    const float4* X4 = (const float4*)X;
    float4 xr[8];
    #pragma unroll
    for (int kc = 0; kc < 4; kc++) {
        if (valid) {
            int gidx = arow * 32 + kc * 8 + quad * 2;
            xr[kc * 2]     = X4[gidx];
            xr[kc * 2 + 1] = X4[gidx + 1];
        } else {
            xr[kc * 2] = xr[kc * 2 + 1] = make_float4(0.f, 0.f, 0.f, 0.f);
        }
    }
    __syncthreads();

    f32x4 acc[8];
    #pragma unroll
    for (int nt = 0; nt < 8; nt++) acc[nt] = (f32x4){0.f, 0.f, 0.f, 0.f};

    #pragma unroll
    for (int kc = 0; kc < 4; kc++) {
        union { unsigned short u[8]; bf16x8 v; } ah, al;
        float f[8] = { xr[kc*2].x, xr[kc*2].y, xr[kc*2].z, xr[kc*2].w,
                       xr[kc*2+1].x, xr[kc*2+1].y, xr[kc*2+1].z, xr[kc*2+1].w };
        #pragma unroll
        for (int j = 0; j < 8; j++) {
            unsigned u = __float_as_uint(f[j]);
            ah.u[j] = (unsigned short)(u >> 16);
            al.u[j] = f2bf(f[j] - __uint_as_float(u & 0xFFFF0000u));
        }
        const int sgbase = (kc * 4 + quad);
        #pragma unroll
        for (int nt = 0; nt < 8; nt++) {
            const int n = nt * 16 + m16;
            bf16x8 b = *(const bf16x8*)&Wl[n * 128 + ((sgbase ^ m16) << 3)];
            acc[nt] = __builtin_amdgcn_mfma_f32_16x16x32_bf16(ah.v, b, acc[nt], 0, 0, 0);
            acc[nt] = __builtin_amdgcn_mfma_f32_16x16x32_bf16(al.v, b, acc[nt], 0, 0, 0);
        }
    }

    #pragma unroll
    for (int nt = 0; nt < 8; nt++) {
        const int col = nt * 16 + m16;
        const float bc = bias[col];
        #pragma unroll
        for (int r = 0; r < 4; r++) {
            int row = row0 + wv * 16 + quad * 4 + r;
            if (row < nrows) {
                float val = acc[nt][r] + bc;
                if (col < 64) YA[(long)row * 64 + col]        = f2bf(val);
                else          YB[(long)row * 64 + (col - 64)] = f2bf(val);
            }
        }
    }
}

// ---------------- MFMA GEMM (bf16 in): Y = Xbf @ W + bias (1 MFMA per tile) -----------
__global__ __launch_bounds__(256) void mfma_gemm_bf16_kernel(
    const unsigned short* __restrict__ Xbf, const unsigned short* __restrict__ Wt,
    const float* __restrict__ bias, float* __restrict__ Y, int nrows)
{
    __shared__ unsigned short Wl[128 * 128];
    const int t = threadIdx.x;
    const int lane = t & 63;
    const int wv = t >> 6;
    const int row0 = blockIdx.x * 64;
    const int m16 = lane & 15;
    const int quad = lane >> 4;

    {
        const uint4* Wg = (const uint4*)Wt;
        #pragma unroll
        for (int i = 0; i < 8; i++) {
            int gi = t + i * 256;
            int n = gi >> 4, g = gi & 15;
            uint4 v = Wg[gi];
            *(uint4*)&Wl[n * 128 + (((g ^ (n & 15)) << 3))] = v;
        }
    }

    const int arow = row0 + wv * 16 + m16;
    const bool valid = (arow < nrows);
    const uint4* X16 = (const uint4*)Xbf;
    union { uint4 u; bf16x8 v; } xr[4];
    #pragma unroll
    for (int kc = 0; kc < 4; kc++) {
        if (valid) xr[kc].u = X16[arow * 16 + kc * 4 + quad];
        else       xr[kc].u = make_uint4(0, 0, 0, 0);
    }
    __syncthreads();

    f32x4 acc[8];
    #pragma unroll
    for (int nt = 0; nt < 8; nt++) acc[nt] = (f32x4){0.f, 0.f, 0.f, 0.f};

    #pragma unroll
    for (int kc = 0; kc < 4; kc++) {
        const int sgbase = (kc * 4 + quad);
        #pragma unroll
        for (int nt = 0; nt < 8; nt++) {
            const int n = nt * 16 + m16;
            bf16x8 b = *(const bf16x8*)&Wl[n * 128 + ((sgbase ^ m16) << 3)];
            acc[nt] = __builtin_amdgcn_mfma_f32_16x16x32_bf16(xr[kc].v, b, acc[nt], 0, 0, 0);
        }
    }

    #pragma unroll
    for (int nt = 0; nt < 8; nt++) {
        const int col = nt * 16 + m16;
        const float bc = bias[col];
        #pragma unroll
        for (int r = 0; r < 4; r++) {
            int row = row0 + wv * 16 + quad * 4 + r;
            if (row < nrows) Y[(long)row * 128 + col] = acc[nt][r] + bc;
        }
    }
}

// ---------------- fused gather + attention: one wave per (node, feature-half) ----------
// Round-13: round-0 proven loop structure (8-deep batches, VGPR-light, no LDS), but the
// hfb table is split into two 6.4 MB half-tables (cols 0-63 / 64-127; one 128B line per
// row) and blocks are XCD-steered: blockIdx%8 in {0..3} -> half 0, {4..7} -> half 1.
// Each XCD's L2 then holds a 6.4 MB working set (vs 12.8) -> L2 misses drop on the
// ~2.7 TB/s post-L2 path that rounds 0/2 showed to be the wall.
// Heads are independent across halves: head = (node*8 + (col>>4))/NN stays within-half.
__global__ __launch_bounds__(256) void gather_attn_kernel(
    const unsigned short* __restrict__ hfA, const unsigned short* __restrict__ hfB,
    const unsigned short* __restrict__ csr1, const int* __restrict__ start1,
    const int* __restrict__ deg1, const float* __restrict__ norm1,
    const unsigned short* __restrict__ csr2, const int* __restrict__ start2,
    const int* __restrict__ deg2, const float* __restrict__ norm2,
    const float* __restrict__ al, const float* __restrict__ ar,
    unsigned short* __restrict__ outb)
{
    const int lane = threadIdx.x & 63;
    const int wv = threadIdx.x >> 6;
    const int b = blockIdx.x;
    const int half = (b >> 2) & 1;                 // XCD steer: b%8<4 -> half0
    const int lb = (b >> 3) * 4 + (b & 3);         // local block within half [0,12500)
    int node = lb * 4 + wv;                        // 12500*4 = 50000 exactly
    node = __builtin_amdgcn_readfirstlane(node);   // wave-uniform -> SGPR
    const unsigned short* tbl = half ? hfB : hfA;

    // own-feature load (attention self term) — independent, issue first
    const float uf = bf2f(tbl[(long)node * 64 + lane]);

    float acc1 = 0.f, acc2 = 0.f;

    #pragma unroll 1
    for (int g = 0; g < 2; g++) {
        const unsigned short* csr = g ? csr2 : csr1;
        const int* startp = g ? start2 : start1;
        const int* degp   = g ? deg2 : deg1;
        const float* norm = g ? norm2 : norm1;
        float acc = 0.f;
        const int st = startp[node], dg = degp[node];
        for (int base = 0; base < dg; base += 64) {
            const int nb = min(64, dg - base);
            int myc = (lane < nb) ? (int)csr[st + base + lane] : 0;  // coalesced
            int j = 0;
            for (; j + 8 <= nb; j += 8) {
                int s[8]; float n[8]; unsigned short u[8];
                #pragma unroll
                for (int q = 0; q < 8; q++) s[q] = __builtin_amdgcn_readlane(myc, j + q);
                #pragma unroll
                for (int q = 0; q < 8; q++) {
                    n[q] = norm[s[q]];
                    u[q] = tbl[(long)s[q] * 64 + lane];   // one 128B line per edge
                }
                #pragma unroll
                for (int q = 0; q < 8; q++)
                    acc = fmaf(bf2f(u[q]), n[q], acc);
            }
            for (; j < nb; j++) {
                int s = __builtin_amdgcn_readlane(myc, j);
                float nv = norm[s];
                unsigned short u = tbl[(long)s * 64 + lane];
                acc = fmaf(bf2f(u), nv, acc);
            }
        }
        if (g) acc2 = acc; else acc1 = acc;
    }

    const float nn1 = norm1[node], nn2 = norm2[node];
    acc1 *= nn1;
    acc2 *= nn2;

    // attention combine in flat-reshape space: lane owns col c = half*64 + lane
    const int c = half * 64 + lane;
    const int cc = c >> 4;
    const int m = node * 8 + cc;
    const int head = m / NN;
    const int hid = c & 15;
    const float av = al[head * 16 + hid];
    const float rv = ar[head * 16 + hid];
    float s_ai = uf * av;
    float s1 = acc1 * rv;
    float s2 = acc2 * rv;
    // reduce over the 16-lane group (one 16-col chunk)
    s_ai += __shfl_xor(s_ai, 1); s_ai += __shfl_xor(s_ai, 2);
    s_ai += __shfl_xor(s_ai, 4); s_ai += __shfl_xor(s_ai, 8);
    s1   += __shfl_xor(s1, 1);   s1   += __shfl_xor(s1, 2);
    s1   += __shfl_xor(s1, 4);   s1   += __shfl_xor(s1, 8);
    s2   += __shfl_xor(s2, 1);   s2   += __shfl_xor(s2, 2);
    s2   += __shfl_xor(s2, 4);   s2   += __shfl_xor(s2, 8);
    float x1 = s_ai + s1; x1 = x1 > 0.f ? x1 : 0.2f * x1;
    float x2 = s_ai + s2; x2 = x2 > 0.f ? x2 : 0.2f * x2;
    float e1 = fminf(expf(x1), 10.f);
    float e2 = fminf(expf(x2), 10.f);
    float inv = 1.f / (e1 + e2);
    float w1 = e1 * inv, w2 = e2 * inv;
    float o = w1 * acc1 + w2 * acc2;
    outb[(long)node * 128 + c] = f2bf(o);          // 64 lanes x u16 = 128B coalesced
}

extern "C" void kernel_launch(void* const* d_in, const int* in_sizes, int n_in,
                              void* d_out, int out_size, void* d_ws, size_t ws_size,
                              hipStream_t stream)
{
    const float* h     = (const float*)d_in[0];
    const int*   src1  = (const int*)  d_in[1];
    const int*   dst1  = (const int*)  d_in[2];
    const int*   src2  = (const int*)  d_in[3];
    const int*   dst2  = (const int*)  d_in[4];
    const float* norm1 = (const float*)d_in[5];
    const float* norm2 = (const float*)d_in[6];
    const float* W_lin = (const float*)d_in[7];
    const float* b_lin = (const float*)d_in[8];
    const float* al    = (const float*)d_in[9];
    const float* ar    = (const float*)d_in[10];
    const float* W_fc  = (const float*)d_in[11];
    const float* b_fc  = (const float*)d_in[12];
    float* out = (float*)d_out;

    // workspace layout
    unsigned short* hfA  = (unsigned short*)d_ws;         // NN*64 bf16 = 6.4 MB (cols 0-63)
    unsigned short* hfB  = hfA + (size_t)NN * 64;         // NN*64 bf16 = 6.4 MB (cols 64-127)
    unsigned short* outbf = hfB + (size_t)NN * 64;        // NN*128 bf16 = 12.8 MB
    unsigned int* bin1 = (unsigned int*)(outbf + (size_t)NN * 128);  // NE u32
    unsigned int* bin2 = bin1 + NE;                       // NE u32
    unsigned short* csr1 = (unsigned short*)(bin2 + NE);  // NE u16
    unsigned short* csr2 = csr1 + NE;                     // NE u16
    unsigned short* WtL  = csr2 + NE;                     // 16384 u16
    unsigned short* WtF  = WtL + 128 * 128;               // 16384 u16
    int* histG  = (int*)(WtF + 128 * 128);                // NBLK*NBG ints = 200 KB
    int* btot   = histG + NBLK * NBG;                     // 392
    int* bbase  = btot + NBG;                             // 392
    int* start1 = bbase + NBG;
    int* start2 = start1 + NN;
    int* deg1   = start2 + NN;
    int* deg2   = deg1 + NN;

    // 1) histogram (chunk-major) + one-time W bf16 conversion
    histA_kernel<<<NBLK + 2, 1024, 0, stream>>>(dst1, dst2, histG, W_lin, W_fc, WtL, WtF);

    // 2) hfA/hfB = bf16(h @ W_lin + b_lin), split by column half
    mfma_gemm_kernel<<<(NN + 63) / 64, 256, 0, stream>>>(h, WtL, b_lin, hfA, hfB, NN);

    // 3) deterministic scatter (computes its own prefix sums; publishes bbase/btot)
    scatterC_kernel<<<NBLK, 1024, 0, stream>>>(src1, dst1, src2, dst2, histG,
                                               bbase, btot, bin1, bin2);

    // 4) per-bucket LDS counting sort -> u16 CSR + start/deg
    bucket_sort_kernel<<<NBG, 256, 0, stream>>>(bin1, bin2, bbase, btot,
                                                csr1, start1, deg1,
                                                csr2, start2, deg2);

    // 5) fused gather (both graphs, split feature halves, XCD-steered) + attention
    gather_attn_kernel<<<25000, 256, 0, stream>>>(
        hfA, hfB,
        csr1, start1, deg1, norm1,
        csr2, start2, deg2, norm2,
        al, ar, outbf);

    // 6) out = outbf @ W_fc + b_fc
    mfma_gemm_bf16_kernel<<<(NN + 63) / 64, 256, 0, stream>>>(outbf, WtF, b_fc, out, NN);
}

// Round 5
// 242.087 us; speedup vs baseline: 1.1946x; 1.0747x over previous
//
#include <hip/hip_runtime.h>

#define NN 50000
#define NE 800000
#define NB 196          // ceil(NN/256) node buckets of 256 nodes
#define NBG 392         // 2*NB (both graphs)
#define NBLK 128        // edge chunks
#define CHUNK 6250      // NE / NBLK exactly
#define MAXB 6144       // max edges per bucket (mean 4081; +32 sigma)
// D = 128 features, HEADS=8, HID=16

typedef __bf16 bf16x8 __attribute__((ext_vector_type(8)));
typedef float  f32x4  __attribute__((ext_vector_type(4)));

__device__ __forceinline__ unsigned short f2bf(float x) {
    unsigned u = __float_as_uint(x);
    return (unsigned short)((u + 0x7FFFu + ((u >> 16) & 1u)) >> 16);   // RNE
}
__device__ __forceinline__ float bflo(unsigned u) { return __uint_as_float(u << 16); }
__device__ __forceinline__ float bfhi(unsigned u) { return __uint_as_float(u & 0xFFFF0000u); }
__device__ __forceinline__ unsigned pack2(float a, float b) {
    return (unsigned)f2bf(a) | ((unsigned)f2bf(b) << 16);
}

// ---------------- phase A: per-chunk LDS histogram (chunk-major histG) + W convert ----
__global__ __launch_bounds__(1024) void histA_kernel(
    const int* __restrict__ dst1, const int* __restrict__ dst2, int* __restrict__ histG,
    const float* __restrict__ Wa, const float* __restrict__ Wb,
    unsigned short* __restrict__ Wta, unsigned short* __restrict__ Wtb)
{
    const int t = threadIdx.x, blk = blockIdx.x;
    if (blk >= NBLK) {   // W convert
        const float* W = (blk - NBLK) ? Wb : Wa;
        unsigned short* Wt = (blk - NBLK) ? Wtb : Wta;
        for (int j = t; j < 128 * 128; j += 1024) {
            int n = j >> 7, k = j & 127;
            Wt[j] = f2bf(W[k * 128 + n]);
        }
        return;
    }
    __shared__ int h[NBG];
    for (int i = t; i < NBG; i += 1024) h[i] = 0;
    __syncthreads();
    const int base = blk * CHUNK;
    for (int i = t; i < CHUNK; i += 1024) {
        atomicAdd(&h[dst1[base + i] >> 8], 1);
        atomicAdd(&h[NB + (dst2[base + i] >> 8)], 1);
    }
    __syncthreads();
    for (int i = t; i < NBG; i += 1024)
        histG[blk * NBG + i] = h[i];
}

// ---------------- phase C: scatter with LOCAL prefix computation ---------------------
__global__ __launch_bounds__(1024) void scatterC_kernel(
    const int* __restrict__ src1, const int* __restrict__ dst1,
    const int* __restrict__ src2, const int* __restrict__ dst2,
    const int* __restrict__ histG,
    int* __restrict__ gbbase, int* __restrict__ gbtot,
    unsigned int* __restrict__ bin1, unsigned int* __restrict__ bin2)
{
    __shared__ int s[512];
    __shared__ int pos[NBG];
    const int t = threadIdx.x, blk = blockIdx.x;

    int total_i = 0, pref_i = 0;
    if (t < NBG) {
        for (int c = 0; c < NBLK; c++) {
            int v = histG[c * NBG + t];          // coalesced across t
            total_i += v;
            if (c < blk) pref_i += v;
        }
    }
    if (t < 512) s[t] = (t < NBG) ? total_i : 0;
    __syncthreads();
    for (int off = 1; off < 512; off <<= 1) {
        int x = 0;
        if (t < 512 && t >= off) x = s[t - off];
        __syncthreads();
        if (t < 512) s[t] += x;
        __syncthreads();
    }
    const int sumG1 = s[NB - 1];   // inclusive over graph-1 buckets
    if (t < NBG) {
        int excl = s[t] - total_i;
        int bb = excl - ((t >= NB) ? sumG1 : 0);   // per-graph exclusive base
        pos[t] = bb + pref_i;
        if (blk == 0) { gbbase[t] = bb; gbtot[t] = total_i; }
    }
    __syncthreads();

    const int base = blk * CHUNK;
    for (int i = t; i < CHUNK; i += 1024) {
        int d = dst1[base + i], sv = src1[base + i];
        int slot = atomicAdd(&pos[d >> 8], 1);
        bin1[slot] = ((unsigned)(d & 255) << 16) | (unsigned)sv;
        d = dst2[base + i]; sv = src2[base + i];
        slot = atomicAdd(&pos[NB + (d >> 8)], 1);
        bin2[slot] = ((unsigned)(d & 255) << 16) | (unsigned)sv;
    }
}

// ---------------- bucket sort: LDS counting sort per bucket, coalesced csr flush ------
__global__ __launch_bounds__(256) void bucket_sort_kernel(
    const unsigned int* __restrict__ bin1, const unsigned int* __restrict__ bin2,
    const int* __restrict__ bbase, const int* __restrict__ btot,
    unsigned short* __restrict__ csr1, int* __restrict__ start1, int* __restrict__ deg1,
    unsigned short* __restrict__ csr2, int* __restrict__ start2, int* __restrict__ deg2)
{
    __shared__ int lcnt[256];
    __shared__ int sc[256];
    __shared__ int oat[256];
    __shared__ unsigned short outb[MAXB];
    const int t = threadIdx.x;
    const int g = (blockIdx.x >= NB) ? 1 : 0;
    const int b = blockIdx.x - g * NB;
    const unsigned int* bin = g ? bin2 : bin1;
    unsigned short* csr = g ? csr2 : csr1;
    int* start = g ? start2 : start1;
    int* deg   = g ? deg2 : deg1;

    const int base = bbase[g * NB + b];
    const int tot = min(btot[g * NB + b], MAXB);

    lcnt[t] = 0;
    __syncthreads();
    for (int i = t; i < tot; i += 256) atomicAdd(&lcnt[bin[base + i] >> 16], 1);
    __syncthreads();
    sc[t] = lcnt[t];
    __syncthreads();
    for (int off = 1; off < 256; off <<= 1) {
        int x = (t >= off) ? sc[t - off] : 0;
        __syncthreads();
        sc[t] += x;
        __syncthreads();
    }
    const int ex = sc[t] - lcnt[t];
    oat[t] = ex;
    __syncthreads();
    for (int i = t; i < tot; i += 256) {
        unsigned v = bin[base + i];
        int slot = atomicAdd(&oat[v >> 16], 1);
        outb[slot] = (unsigned short)(v & 0xFFFFu);
    }
    __syncthreads();
    for (int i = t; i < tot; i += 256) csr[base + i] = outb[i];
    int nd = b * 256 + t;
    if (nd < NN) { start[nd] = base + ex; deg[nd] = lcnt[t]; }
}

// ---------------- MFMA GEMM (fp32 in): Ybf = bf16(X @ W + bias) -----------------------
__global__ __launch_bounds__(256) void mfma_gemm_kernel(
    const float* __restrict__ X, const unsigned short* __restrict__ Wt,
    const float* __restrict__ bias, unsigned short* __restrict__ Ybf, int nrows)
{
    __shared__ unsigned short Wl[128 * 128];   // 32 KB, granule-swizzled
    const int t = threadIdx.x;
    const int lane = t & 63;
    const int wv = t >> 6;
    const int row0 = blockIdx.x * 64;
    const int m16 = lane & 15;
    const int quad = lane >> 4;

    {
        const uint4* Wg = (const uint4*)Wt;
        #pragma unroll
        for (int i = 0; i < 8; i++) {
            int gi = t + i * 256;
            int n = gi >> 4, g = gi & 15;
            uint4 v = Wg[gi];
            *(uint4*)&Wl[n * 128 + (((g ^ (n & 15)) << 3))] = v;
        }
    }

    const int arow = row0 + wv * 16 + m16;
    const bool valid = (arow < nrows);
    const float4* X4 = (const float4*)X;
    float4 xr[8];
    #pragma unroll
    for (int kc = 0; kc < 4; kc++) {
        if (valid) {
            int gidx = arow * 32 + kc * 8 + quad * 2;
            xr[kc * 2]     = X4[gidx];
            xr[kc * 2 + 1] = X4[gidx + 1];
        } else {
            xr[kc * 2] = xr[kc * 2 + 1] = make_float4(0.f, 0.f, 0.f, 0.f);
        }
    }
    __syncthreads();

    f32x4 acc[8];
    #pragma unroll
    for (int nt = 0; nt < 8; nt++) acc[nt] = (f32x4){0.f, 0.f, 0.f, 0.f};

    #pragma unroll
    for (int kc = 0; kc < 4; kc++) {
        union { unsigned short u[8]; bf16x8 v; } ah, al;
        float f[8] = { xr[kc*2].x, xr[kc*2].y, xr[kc*2].z, xr[kc*2].w,
                       xr[kc*2+1].x, xr[kc*2+1].y, xr[kc*2+1].z, xr[kc*2+1].w };
        #pragma unroll
        for (int j = 0; j < 8; j++) {
            unsigned u = __float_as_uint(f[j]);
            ah.u[j] = (unsigned short)(u >> 16);
            al.u[j] = f2bf(f[j] - __uint_as_float(u & 0xFFFF0000u));
        }
        const int sgbase = (kc * 4 + quad);
        #pragma unroll
        for (int nt = 0; nt < 8; nt++) {
            const int n = nt * 16 + m16;
            bf16x8 b = *(const bf16x8*)&Wl[n * 128 + ((sgbase ^ m16) << 3)];
            acc[nt] = __builtin_amdgcn_mfma_f32_16x16x32_bf16(ah.v, b, acc[nt], 0, 0, 0);
            acc[nt] = __builtin_amdgcn_mfma_f32_16x16x32_bf16(al.v, b, acc[nt], 0, 0, 0);
        }
    }

    #pragma unroll
    for (int nt = 0; nt < 8; nt++) {
        const int col = nt * 16 + m16;
        const float bc = bias[col];
        #pragma unroll
        for (int r = 0; r < 4; r++) {
            int row = row0 + wv * 16 + quad * 4 + r;
            if (row < nrows) Ybf[(long)row * 128 + col] = f2bf(acc[nt][r] + bc);
        }
    }
}

// ---------------- MFMA GEMM (bf16 in): Y = Xbf @ W + bias (1 MFMA per tile) -----------
__global__ __launch_bounds__(256) void mfma_gemm_bf16_kernel(
    const unsigned short* __restrict__ Xbf, const unsigned short* __restrict__ Wt,
    const float* __restrict__ bias, float* __restrict__ Y, int nrows)
{
    __shared__ unsigned short Wl[128 * 128];
    const int t = threadIdx.x;
    const int lane = t & 63;
    const int wv = t >> 6;
    const int row0 = blockIdx.x * 64;
    const int m16 = lane & 15;
    const int quad = lane >> 4;

    {
        const uint4* Wg = (const uint4*)Wt;
        #pragma unroll
        for (int i = 0; i < 8; i++) {
            int gi = t + i * 256;
            int n = gi >> 4, g = gi & 15;
            uint4 v = Wg[gi];
            *(uint4*)&Wl[n * 128 + (((g ^ (n & 15)) << 3))] = v;
        }
    }

    const int arow = row0 + wv * 16 + m16;
    const bool valid = (arow < nrows);
    const uint4* X16 = (const uint4*)Xbf;
    union { uint4 u; bf16x8 v; } xr[4];
    #pragma unroll
    for (int kc = 0; kc < 4; kc++) {
        if (valid) xr[kc].u = X16[arow * 16 + kc * 4 + quad];
        else       xr[kc].u = make_uint4(0, 0, 0, 0);
    }
    __syncthreads();

    f32x4 acc[8];
    #pragma unroll
    for (int nt = 0; nt < 8; nt++) acc[nt] = (f32x4){0.f, 0.f, 0.f, 0.f};

    #pragma unroll
    for (int kc = 0; kc < 4; kc++) {
        const int sgbase = (kc * 4 + quad);
        #pragma unroll
        for (int nt = 0; nt < 8; nt++) {
            const int n = nt * 16 + m16;
            bf16x8 b = *(const bf16x8*)&Wl[n * 128 + ((sgbase ^ m16) << 3)];
            acc[nt] = __builtin_amdgcn_mfma_f32_16x16x32_bf16(xr[kc].v, b, acc[nt], 0, 0, 0);
        }
    }

    #pragma unroll
    for (int nt = 0; nt < 8; nt++) {
        const int col = nt * 16 + m16;
        const float bc = bias[col];
        #pragma unroll
        for (int r = 0; r < 4; r++) {
            int row = row0 + wv * 16 + quad * 4 + r;
            if (row < nrows) Y[(long)row * 128 + col] = acc[nt][r] + bc;
        }
    }
}

// ---------------- fused gather + attention: one wave per node, ONE latency exposure ----
// Round-14: lane reads dwordx4 (16B = 8 cols); a 16-lane quarter covers one 256B row,
// so ONE instruction gathers 4 edge rows. 8 instrs = 32 edges (>= deg for 99.98% of
// nodes). Both graphs' groups issued back-to-back (16 instrs, 64 payload VGPRs) before
// any consume -> ~1 latency exposure per node (round-0 had ~4). __launch_bounds__(256,4)
// raises the VGPR budget to 128 so the compiler does NOT register-schedule the pipeline
// away (mechanism behind rounds 1-2 failures: default budget 64 targets 8 waves/SIMD).
// Norms: one lane-parallel load per 64-edge chunk + ds_bpermute redistribution.
__global__ __launch_bounds__(256, 4) void gather_attn_kernel(
    const unsigned short* __restrict__ hfb,
    const unsigned short* __restrict__ csr1, const int* __restrict__ start1,
    const int* __restrict__ deg1, const float* __restrict__ norm1,
    const unsigned short* __restrict__ csr2, const int* __restrict__ start2,
    const int* __restrict__ deg2, const float* __restrict__ norm2,
    const float* __restrict__ al, const float* __restrict__ ar,
    unsigned short* __restrict__ outb)
{
    const int lane = threadIdx.x & 63;
    const int wv = threadIdx.x >> 6;
    int node = blockIdx.x * 4 + wv;                // 12500*4 = 50000 exactly
    node = __builtin_amdgcn_readfirstlane(node);   // wave-uniform -> SGPR
    const char* tblb = (const char*)hfb;
    const int qtr = lane >> 4;                     // quarter handles edges == qtr mod 4
    const int sub16 = (lane & 15) * 16;            // byte offset within 256B row

    // own-feature row (attention self term): lane holds cols [8m, 8m+8), m = lane&15
    const uint4 ufv = *(const uint4*)(tblb + ((long)node << 8) + sub16);

    const int st1 = start1[node], dg1 = deg1[node];
    const int st2 = start2[node], dg2 = deg2[node];

// issue one 32-edge group (8 dwordx4 gathers; 4 edges per instr, clamped+masked tail)
#define GA_ISSUE(vv, nn_, myc, nv, j0, nb)                                 \
    _Pragma("unroll")                                                      \
    for (int k = 0; k < 8; k++) {                                          \
        int e = (j0) + 4 * k + qtr;                                        \
        int ec = (e < (nb)) ? e : 0;                                       \
        int sx = __shfl((myc), ec);                                        \
        float nq = __shfl((nv), ec);                                       \
        nn_[k] = (e < (nb)) ? nq : 0.f;                                    \
        vv[k] = *(const uint4*)(tblb + (((long)sx) << 8) + sub16);         \
    }

#define GA_CONSUME(vv, nn_, acc)                                           \
    _Pragma("unroll")                                                      \
    for (int k = 0; k < 8; k++) {                                          \
        const float n = nn_[k];                                            \
        acc[0] = fmaf(bflo(vv[k].x), n, acc[0]);                           \
        acc[1] = fmaf(bfhi(vv[k].x), n, acc[1]);                           \
        acc[2] = fmaf(bflo(vv[k].y), n, acc[2]);                           \
        acc[3] = fmaf(bfhi(vv[k].y), n, acc[3]);                           \
        acc[4] = fmaf(bflo(vv[k].z), n, acc[4]);                           \
        acc[5] = fmaf(bfhi(vv[k].z), n, acc[5]);                           \
        acc[6] = fmaf(bflo(vv[k].w), n, acc[6]);                           \
        acc[7] = fmaf(bfhi(vv[k].w), n, acc[7]);                           \
    }

    float acc1[8] = {0,0,0,0,0,0,0,0}, acc2[8] = {0,0,0,0,0,0,0,0};

    if (__builtin_expect(dg1 <= 64 && dg2 <= 64, 1)) {
        // fast path: whole neighbor lists fit one csr chunk each
        int myc1 = (lane < dg1) ? (int)csr1[st1 + lane] : 0;   // coalesced u16
        int myc2 = (lane < dg2) ? (int)csr2[st2 + lane] : 0;
        const float nv1 = norm1[myc1];                         // lane-parallel
        const float nv2 = norm2[myc2];

        uint4 vA[8], vB[8]; float nA[8], nB[8];
        GA_ISSUE(vA, nA, myc1, nv1, 0, dg1)
        GA_ISSUE(vB, nB, myc2, nv2, 0, dg2)
        __builtin_amdgcn_sched_barrier(0);
        GA_CONSUME(vA, nA, acc1)
        GA_CONSUME(vB, nB, acc2)
        if (dg1 > 32) {            // ~0.01% of nodes
            GA_ISSUE(vA, nA, myc1, nv1, 32, dg1)
            __builtin_amdgcn_sched_barrier(0);
            GA_CONSUME(vA, nA, acc1)
        }
        if (dg2 > 32) {
            GA_ISSUE(vB, nB, myc2, nv2, 32, dg2)
            __builtin_amdgcn_sched_barrier(0);
            GA_CONSUME(vB, nB, acc2)
        }
    } else {
        // general path (deg > 64: essentially never on this data, correctness only)
        #pragma unroll 1
        for (int g = 0; g < 2; g++) {
            const unsigned short* csr = g ? csr2 : csr1;
            const int st = g ? st2 : st1;
            const int dg = g ? dg2 : dg1;
            const float* norm = g ? norm2 : norm1;
            float* acc = g ? acc2 : acc1;
            for (int base = 0; base < dg; base += 64) {
                const int nb = min(64, dg - base);
                int myc = (lane < nb) ? (int)csr[st + base + lane] : 0;
                const float nv = norm[myc];
                for (int j = 0; j < nb; j += 32) {
                    uint4 vv[8]; float nn_[8];
                    GA_ISSUE(vv, nn_, myc, nv, j, nb)
                    __builtin_amdgcn_sched_barrier(0);
                    GA_CONSUME(vv, nn_, acc)
                }
            }
        }
    }
#undef GA_ISSUE
#undef GA_CONSUME

    // fold quarters: col c's total = sum over the 4 lanes {m, m+16, m+32, m+48}
    #pragma unroll
    for (int i = 0; i < 8; i++) {
        acc1[i] += __shfl_xor(acc1[i], 16);
        acc1[i] += __shfl_xor(acc1[i], 32);
        acc2[i] += __shfl_xor(acc2[i], 16);
        acc2[i] += __shfl_xor(acc2[i], 32);
    }

    // outer (dst) norm
    const float nn1 = norm1[node], nn2 = norm2[node];

    // attention combine in flat-reshape space: lane owns cols [8m, 8m+8), m = lane&15
    const int m = lane & 15;
    const int head = (node * 8 + (m >> 1)) / NN;
    const int hb = head * 16 + ((m & 1) << 3);     // hid base for this lane's 8 cols
    float uff[8] = { bflo(ufv.x), bfhi(ufv.x), bflo(ufv.y), bfhi(ufv.y),
                     bflo(ufv.z), bfhi(ufv.z), bflo(ufv.w), bfhi(ufv.w) };
    float s_ai = 0.f, s1 = 0.f, s2 = 0.f;
    #pragma unroll
    for (int i = 0; i < 8; i++) {
        acc1[i] *= nn1;
        acc2[i] *= nn2;
        const float avi = al[hb + i], rvi = ar[hb + i];
        s_ai = fmaf(uff[i], avi, s_ai);
        s1   = fmaf(acc1[i], rvi, s1);
        s2   = fmaf(acc2[i], rvi, s2);
    }
    // 16-col block = lanes {2t, 2t+1} within the 16-lane group
    s_ai += __shfl_xor(s_ai, 1);
    s1   += __shfl_xor(s1, 1);
    s2   += __shfl_xor(s2, 1);

    float x1 = s_ai + s1; x1 = x1 > 0.f ? x1 : 0.2f * x1;
    float x2 = s_ai + s2; x2 = x2 > 0.f ? x2 : 0.2f * x2;
    float e1 = fminf(expf(x1), 10.f);
    float e2 = fminf(expf(x2), 10.f);
    float inv = 1.f / (e1 + e2);
    float w1 = e1 * inv, w2 = e2 * inv;

    if (lane < 16) {   // quarters hold duplicates; quarter 0 writes 16x16B = 256B
        uint4 w;
        w.x = pack2(w1 * acc1[0] + w2 * acc2[0], w1 * acc1[1] + w2 * acc2[1]);
        w.y = pack2(w1 * acc1[2] + w2 * acc2[2], w1 * acc1[3] + w2 * acc2[3]);
        w.z = pack2(w1 * acc1[4] + w2 * acc2[4], w1 * acc1[5] + w2 * acc2[5]);
        w.w = pack2(w1 * acc1[6] + w2 * acc2[6], w1 * acc1[7] + w2 * acc2[7]);
        *(uint4*)((char*)outb + ((long)node << 8) + m * 16) = w;
    }
}

extern "C" void kernel_launch(void* const* d_in, const int* in_sizes, int n_in,
                              void* d_out, int out_size, void* d_ws, size_t ws_size,
                              hipStream_t stream)
{
    const float* h     = (const float*)d_in[0];
    const int*   src1  = (const int*)  d_in[1];
    const int*   dst1  = (const int*)  d_in[2];
    const int*   src2  = (const int*)  d_in[3];
    const int*   dst2  = (const int*)  d_in[4];
    const float* norm1 = (const float*)d_in[5];
    const float* norm2 = (const float*)d_in[6];
    const float* W_lin = (const float*)d_in[7];
    const float* b_lin = (const float*)d_in[8];
    const float* al    = (const float*)d_in[9];
    const float* ar    = (const float*)d_in[10];
    const float* W_fc  = (const float*)d_in[11];
    const float* b_fc  = (const float*)d_in[12];
    float* out = (float*)d_out;

    // workspace layout
    unsigned short* hfb  = (unsigned short*)d_ws;         // NN*128 bf16 = 12.8 MB
    unsigned short* outbf = hfb + (size_t)NN * 128;       // NN*128 bf16 = 12.8 MB
    unsigned int* bin1 = (unsigned int*)(outbf + (size_t)NN * 128);  // NE u32
    unsigned int* bin2 = bin1 + NE;                       // NE u32
    unsigned short* csr1 = (unsigned short*)(bin2 + NE);  // NE u16
    unsigned short* csr2 = csr1 + NE;                     // NE u16
    unsigned short* WtL  = csr2 + NE;                     // 16384 u16
    unsigned short* WtF  = WtL + 128 * 128;               // 16384 u16
    int* histG  = (int*)(WtF + 128 * 128);                // NBLK*NBG ints = 200 KB
    int* btot   = histG + NBLK * NBG;                     // 392
    int* bbase  = btot + NBG;                             // 392
    int* start1 = bbase + NBG;
    int* start2 = start1 + NN;
    int* deg1   = start2 + NN;
    int* deg2   = deg1 + NN;

    // 1) histogram (chunk-major) + one-time W bf16 conversion
    histA_kernel<<<NBLK + 2, 1024, 0, stream>>>(dst1, dst2, histG, W_lin, W_fc, WtL, WtF);

    // 2) hfb = bf16(h @ W_lin + b_lin)
    mfma_gemm_kernel<<<(NN + 63) / 64, 256, 0, stream>>>(h, WtL, b_lin, hfb, NN);

    // 3) deterministic scatter (computes its own prefix sums; publishes bbase/btot)
    scatterC_kernel<<<NBLK, 1024, 0, stream>>>(src1, dst1, src2, dst2, histG,
                                               bbase, btot, bin1, bin2);

    // 4) per-bucket LDS counting sort -> u16 CSR + start/deg
    bucket_sort_kernel<<<NBG, 256, 0, stream>>>(bin1, bin2, bbase, btot,
                                                csr1, start1, deg1,
                                                csr2, start2, deg2);

    // 5) fused gather (both graphs) + attention combine -> bf16
    gather_attn_kernel<<<12500, 256, 0, stream>>>(
        hfb,
        csr1, start1, deg1, norm1,
        csr2, start2, deg2, norm2,
        al, ar, outbf);

    // 6) out = outbf @ W_fc + b_fc
    mfma_gemm_bf16_kernel<<<(NN + 63) / 64, 256, 0, stream>>>(outbf, WtF, b_fc, out, NN);
}